// Round 1
// baseline (124.987 us; speedup 1.0000x reference)
//
#include <hip/hip_runtime.h>
#include <math.h>

// ---------------------------------------------------------------------------
// HyperbolicInfoNCE on MI355X — Round 7: 3-waves/SIMD occupancy + A-hoist.
//
// R6 post-mortem: gemm_epilogue = 57us with MfmaUtil 14%, VALUBusy 42%,
// HBM 4%, occupancy 19%. ~25us of stall: 112 arch VGPR + 64 acc AGPR = 176
// combined (unified file) -> 2 waves/SIMD; epilogue of one wave can't cover
// the other wave's L2 latency.
//
// R7: wave tile 64x64 -> 32x64 (acc 64->32 regs); A operand hoisted to
// registers (Ah[2][5] = 40 VGPRs, loaded ONCE, reused across 8 col-tiles);
// block = 4 waves stacked vertically sharing one B-tile per col-tile (L1
// reuse). Combined regs ~140 -> __launch_bounds__(256,3) -> 3 waves/SIMD.
// Same grid (1024), same strip/chunk L2 mapping, no LDS, no fences.
// ---------------------------------------------------------------------------

#define BDIM   8192
#define K_IN   129
#define K_PAD  160      // 5 * 32
#define BK     32
#define NKT    (K_PAD / BK)   // 5
#define CTILES 8              // 64-col tiles per block (128 rows x 512 cols)

typedef __bf16  bf16x8 __attribute__((ext_vector_type(8)));
typedef float   f32x4  __attribute__((ext_vector_type(4)));

// ws layout (bytes)
#define OFF_A    0u
#define OFF_B    (BDIM * K_PAD * 2u)                  // 2,621,440
#define OFF_RS   (2u * BDIM * K_PAD * 2u)             // 5,242,880
#define OFF_CP   (OFF_RS + BDIM * 4u)                 // 4 replicas of col sums
#define OFF_DG   (OFF_CP + 4u * BDIM * 4u)

// ---- hardware transcendentals (v_sqrt_f32 / v_log_f32 / v_exp_f32) ----
__device__ __forceinline__ float fast_sqrt(float x) {
#if __has_builtin(__builtin_amdgcn_sqrtf)
    return __builtin_amdgcn_sqrtf(x);
#else
    return sqrtf(x);
#endif
}
__device__ __forceinline__ float fast_log2(float x) {
#if __has_builtin(__builtin_amdgcn_logf)
    return __builtin_amdgcn_logf(x);       // log base 2
#else
    return __log2f(x);
#endif
}
__device__ __forceinline__ float fast_exp2(float x) {
#if __has_builtin(__builtin_amdgcn_exp2f)
    return __builtin_amdgcn_exp2f(x);      // 2^x
#else
    extern "C" __device__ float __ocml_native_exp2_f32(float);
    return __ocml_native_exp2_f32(x);
#endif
}

__device__ __forceinline__ unsigned short f2bf_rne(float f) {
    unsigned int u = __float_as_uint(f);
    u += 0x7FFFu + ((u >> 16) & 1u);   // round-to-nearest-even
    return (unsigned short)(u >> 16);
}

// ---------------------------------------------------------------------------
// Kernel 1: fp32 -> bf16, K zero-padded 129->160, Lorentz metric folded into
// A (negate column 0 of z1). Also zeroes row_sum + 4 col_sum replicas
// (contiguous, 5*BDIM floats). diag is fully overwritten -> no zeroing.
// ---------------------------------------------------------------------------
__global__ __launch_bounds__(256) void convert_kernel(
    const float* __restrict__ z1, const float* __restrict__ z2,
    unsigned short* __restrict__ A, unsigned short* __restrict__ B,
    float* __restrict__ rs_cp)
{
    int idx = blockIdx.x * 256 + threadIdx.x;
    if (idx < 5 * BDIM) rs_cp[idx] = 0.f;
    if (idx >= BDIM * K_PAD) return;
    int r = idx / K_PAD;
    int c = idx - r * K_PAD;
    float va = 0.f, vb = 0.f;
    if (c < K_IN) {
        va = z1[r * K_IN + c];
        vb = z2[r * K_IN + c];
        if (c == 0) va = -va;          // Lorentz metric on first coordinate
    }
    A[idx] = f2bf_rne(va);
    B[idx] = f2bf_rne(vb);
}

// ---------------------------------------------------------------------------
// Kernel 2: strip-GEMM with fused acosh/exp epilogue.
//   grid = 1024: bid = chunk*64 + strip  (consecutive blocks share B-chunk)
//   block: rows [strip*128, +128) x cols [chunk*512, +512)
//   wave w (0..3): rows [strip*128 + w*32, +32), all 8 col-tiles of 64
//   -> all 4 waves read the SAME B-tile per ct (L1 reuse); A is hoisted to
//      registers once per wave (Ah[2][NKT]).
//   fragment layouts (guide-verified, m89/m91):
//     A/B: elem [m=lane&15][k=(lane>>4)*8 + j]
//     C/D: elem [row=(lane>>4)*4 + reg][col=lane&15]
// ---------------------------------------------------------------------------
__global__ __launch_bounds__(256, 3) void gemm_epilogue_kernel(
    const unsigned short* __restrict__ A, const unsigned short* __restrict__ B,
    float* __restrict__ row_sum, float* __restrict__ col_part,
    float* __restrict__ diag)
{
    const int t    = threadIdx.x;
    const int lane = t & 63;
    const int wave = t >> 6;
    const int quad = lane >> 4;
    const int l16  = lane & 15;

    const int strip = blockIdx.x & 63;
    const int chunk = blockIdx.x >> 6;
    const int rowBase  = strip * 128 + wave * 32;   // wave's first row
    const int colChunk = chunk * 512;               // block's first col

    const unsigned short* Abase = A + (rowBase + l16) * K_PAD + quad * 8;
    float* colRep = col_part + (strip & 3) * BDIM;  // contention / 4

    // ---- hoist the entire A operand for this wave: 2 row-frags x 5 k-tiles
    bf16x8 Ah[2][NKT];
    #pragma unroll
    for (int i = 0; i < 2; ++i)
        #pragma unroll
        for (int kt = 0; kt < NKT; ++kt)
            Ah[i][kt] = *(const bf16x8*)(Abase + i * 16 * K_PAD + kt * BK);

    float rowp[2][4] = {};   // persistent across all col-tiles

    for (int ct = 0; ct < CTILES; ++ct) {
        const int colBase = colChunk + ct * 64;
        const unsigned short* Bbase = B + (colBase + l16) * K_PAD + quad * 8;

        f32x4 acc[2][4] = {};
        #pragma unroll
        for (int kt = 0; kt < NKT; ++kt) {
            bf16x8 bfr[4];
            #pragma unroll
            for (int j = 0; j < 4; ++j)
                bfr[j] = *(const bf16x8*)(Bbase + j * 16 * K_PAD + kt * BK);
            #pragma unroll
            for (int i = 0; i < 2; ++i)
                #pragma unroll
                for (int j = 0; j < 4; ++j)
                    acc[i][j] = __builtin_amdgcn_mfma_f32_16x16x32_bf16(
                                    Ah[i][kt], bfr[j], acc[i][j], 0, 0, 0);
        }

        // ---- fused epilogue for this 32x64 tile ----
        // u = x + sqrt(x^2-1), x = max(-inner, 1+1e-6)
        // exp(sims) = exp2(-14.2857142857 * log2(u))
        // sims      = -(ln2/0.07) * log2(u)
        // diag tile: wave rows [rowBase,+32) live in col-tile (rowBase & ~63);
        // sub-tile offset dj = (rowBase & 32)>>4 in {0,2}: diag at j == i+dj.
        const bool diagTile = (colBase == (rowBase & ~63));
        const int  dj       = (rowBase >> 4) & 2;
        float colp[4] = {0.f, 0.f, 0.f, 0.f};

        #pragma unroll
        for (int i = 0; i < 2; ++i) {
            #pragma unroll
            for (int j = 0; j < 4; ++j) {
                #pragma unroll
                for (int reg = 0; reg < 4; ++reg) {
                    float inner = acc[i][j][reg];
                    float x = fmaxf(-inner, 1.000001f);
                    float s = fast_sqrt(__builtin_fmaf(x, x, -1.0f));
                    float l2u = fast_log2(x + s);
                    float e = fast_exp2(-14.285714285714286f * l2u);
                    rowp[i][reg] += e;
                    colp[j]      += e;
                    if (diagTile && (j - i) == dj && (quad * 4 + reg) == l16) {
                        int R = rowBase + i * 16 + quad * 4 + reg;
                        diag[R] = -9.902102579427789f * l2u;
                    }
                }
            }
        }

        // col sums for this tile: reduce across quads (they hold the rows),
        // one atomic per col
        #pragma unroll
        for (int j = 0; j < 4; ++j) {
            float v = colp[j];
            v += __shfl_xor(v, 16);
            v += __shfl_xor(v, 32);
            if (quad == 0)
                atomicAdd(&colRep[colBase + j * 16 + l16], v);
        }
    }

    // row sums: accumulated over all 8 col-tiles; reduce across the 16 lanes
    // of each quad (they hold the cols), one atomic per row
    #pragma unroll
    for (int i = 0; i < 2; ++i) {
        #pragma unroll
        for (int reg = 0; reg < 4; ++reg) {
            float v = rowp[i][reg];
            v += __shfl_xor(v, 1);
            v += __shfl_xor(v, 2);
            v += __shfl_xor(v, 4);
            v += __shfl_xor(v, 8);
            if (l16 == 0)
                atomicAdd(&row_sum[rowBase + i * 16 + quad * 4 + reg], v);
        }
    }
}

// ---------------------------------------------------------------------------
// Kernel 3: loss = mean_b( 0.5*(ln rs[b] + ln cs[b]) - diag[b] ),
// cs[b] = sum of 4 replicas.
// ---------------------------------------------------------------------------
__global__ __launch_bounds__(1024) void finalize_kernel(
    const float* __restrict__ rs, const float* __restrict__ cp,
    const float* __restrict__ dg, float* __restrict__ out)
{
    __shared__ float part[16];
    int t = threadIdx.x;
    float a = 0.f;
    const float LN2_HALF = 0.34657359027997264f;  // 0.5 * ln2
    for (int b = t; b < BDIM; b += 1024) {
        float cs = cp[b] + cp[b + BDIM] + cp[b + 2 * BDIM] + cp[b + 3 * BDIM];
        a += LN2_HALF * (fast_log2(rs[b]) + fast_log2(cs)) - dg[b];
    }
    #pragma unroll
    for (int m = 1; m < 64; m <<= 1) a += __shfl_xor(a, m);
    if ((t & 63) == 0) part[t >> 6] = a;
    __syncthreads();
    if (t < 16) {
        float v = part[t];
        #pragma unroll
        for (int m = 1; m < 16; m <<= 1) v += __shfl_xor(v, m);
        if (t == 0) out[0] = v * (1.0f / (float)BDIM);
    }
}

// ---------------------------------------------------------------------------
extern "C" void kernel_launch(void* const* d_in, const int* in_sizes, int n_in,
                              void* d_out, int out_size, void* d_ws, size_t ws_size,
                              hipStream_t stream)
{
    const float* z1 = (const float*)d_in[0];
    const float* z2 = (const float*)d_in[1];
    float* out = (float*)d_out;

    char* ws = (char*)d_ws;
    unsigned short* A  = (unsigned short*)(ws + OFF_A);
    unsigned short* B  = (unsigned short*)(ws + OFF_B);
    float* row_sum     = (float*)(ws + OFF_RS);
    float* col_part    = (float*)(ws + OFF_CP);
    float* diag        = (float*)(ws + OFF_DG);

    convert_kernel<<<(BDIM * K_PAD + 255) / 256, 256, 0, stream>>>(
        z1, z2, A, B, row_sum /* rs + 4 col replicas contiguous */);

    gemm_epilogue_kernel<<<1024, 256, 0, stream>>>(
        A, B, row_sum, col_part, diag);

    finalize_kernel<<<1, 1024, 0, stream>>>(row_sum, col_part, diag, out);
}

// Round 2
// 121.921 us; speedup vs baseline: 1.0251x; 1.0251x over previous
//
#include <hip/hip_runtime.h>
#include <math.h>

// ---------------------------------------------------------------------------
// HyperbolicInfoNCE on MI355X — Round 8: explicit cross-tile register
// double-buffer to break the col-tile load convoy.
//
// R7 post-mortem: occupancy 19->35% but dur 57->63.5us, VALUBusy flat 40%,
// VGPR_Count=64. Under launch_bounds(256,3) the compiler allocated lazily
// (no prefetch depth); all waves hit each col-tile's 5 kt load groups in
// lockstep -> convoy stall that more waves can't hide. R6 was faster only
// because its 2x bigger tile amortized the same convoy.
//
// R8: wave tile 32x32 per col-tile (CTILES=16, same totals). B-fragments for
// tile ct+1 are loaded into a SECOND named register buffer BEFORE tile ct's
// ~600-cycle transcendental epilogue -> epilogue hides all load latency.
// Named bufA/bufB + 2-step unrolled loop (rule #20: no runtime indexing).
// Regs ~164 <= 170 cap at 3 waves/SIMD. 3 blocks/CU x 10KB shared B-tile
// fits L1. Diag condition now colBase==rowBase && i==j (compile-time pruned).
// ---------------------------------------------------------------------------

#define BDIM   8192
#define K_IN   129
#define K_PAD  160      // 5 * 32
#define BK     32
#define NKT    (K_PAD / BK)   // 5
#define CTILES 16             // 32-col tiles per block (128 rows x 512 cols)

typedef __bf16  bf16x8 __attribute__((ext_vector_type(8)));
typedef float   f32x4  __attribute__((ext_vector_type(4)));

// ws layout (bytes)
#define OFF_A    0u
#define OFF_B    (BDIM * K_PAD * 2u)                  // 2,621,440
#define OFF_RS   (2u * BDIM * K_PAD * 2u)             // 5,242,880
#define OFF_CP   (OFF_RS + BDIM * 4u)                 // 4 replicas of col sums
#define OFF_DG   (OFF_CP + 4u * BDIM * 4u)

// ---- hardware transcendentals (v_sqrt_f32 / v_log_f32 / v_exp_f32) ----
__device__ __forceinline__ float fast_sqrt(float x) {
#if __has_builtin(__builtin_amdgcn_sqrtf)
    return __builtin_amdgcn_sqrtf(x);
#else
    return sqrtf(x);
#endif
}
__device__ __forceinline__ float fast_log2(float x) {
#if __has_builtin(__builtin_amdgcn_logf)
    return __builtin_amdgcn_logf(x);       // log base 2
#else
    return __log2f(x);
#endif
}
__device__ __forceinline__ float fast_exp2(float x) {
#if __has_builtin(__builtin_amdgcn_exp2f)
    return __builtin_amdgcn_exp2f(x);      // 2^x
#else
    extern "C" __device__ float __ocml_native_exp2_f32(float);
    return __ocml_native_exp2_f32(x);
#endif
}

__device__ __forceinline__ unsigned short f2bf_rne(float f) {
    unsigned int u = __float_as_uint(f);
    u += 0x7FFFu + ((u >> 16) & 1u);   // round-to-nearest-even
    return (unsigned short)(u >> 16);
}

// ---------------------------------------------------------------------------
// Kernel 1: fp32 -> bf16, K zero-padded 129->160, Lorentz metric folded into
// A (negate column 0 of z1). Also zeroes row_sum + 4 col_sum replicas.
// ---------------------------------------------------------------------------
__global__ __launch_bounds__(256) void convert_kernel(
    const float* __restrict__ z1, const float* __restrict__ z2,
    unsigned short* __restrict__ A, unsigned short* __restrict__ B,
    float* __restrict__ rs_cp)
{
    int idx = blockIdx.x * 256 + threadIdx.x;
    if (idx < 5 * BDIM) rs_cp[idx] = 0.f;
    if (idx >= BDIM * K_PAD) return;
    int r = idx / K_PAD;
    int c = idx - r * K_PAD;
    float va = 0.f, vb = 0.f;
    if (c < K_IN) {
        va = z1[r * K_IN + c];
        vb = z2[r * K_IN + c];
        if (c == 0) va = -va;          // Lorentz metric on first coordinate
    }
    A[idx] = f2bf_rne(va);
    B[idx] = f2bf_rne(vb);
}

// ---------------------------------------------------------------------------
// Kernel 2: strip-GEMM with fused acosh/exp epilogue, software-pipelined.
//   grid = 1024: bid = chunk*64 + strip  (consecutive blocks share B-chunk)
//   block: rows [strip*128, +128) x cols [chunk*512, +512)
//   wave w (0..3): rows [strip*128 + w*32, +32), 16 col-tiles of 32
//   fragment layouts (guide-verified, m89/m91):
//     A/B operand: elem [m=lane&15][k=(lane>>4)*8 + j]
//     C/D:         elem [row=(lane>>4)*4 + reg][col=lane&15]
// ---------------------------------------------------------------------------

// Load the 10 B-fragments (2 col-frags x 5 k-tiles) of one 32-col tile.
// Fully unrolled -> all buffer indices compile-time (rule #20).
#define LOADB(buf, cb)                                                       \
    {                                                                        \
        const unsigned short* _Bb = B + ((cb) + l16) * K_PAD + quad * 8;     \
        _Pragma("unroll")                                                    \
        for (int _j = 0; _j < 2; ++_j)                                       \
            _Pragma("unroll")                                                \
            for (int _kt = 0; _kt < NKT; ++_kt)                              \
                buf[_j * NKT + _kt] =                                        \
                    *(const bf16x8*)(_Bb + _j * 16 * K_PAD + _kt * BK);      \
    }

// MFMA + fused epilogue for one 32x32 tile using buffer `buf`.
#define COMPUTE(buf, cb)                                                     \
    {                                                                        \
        const int colBase = (cb);                                            \
        f32x4 acc[2][2] = {};                                                \
        _Pragma("unroll")                                                    \
        for (int kt = 0; kt < NKT; ++kt)                                     \
            _Pragma("unroll")                                                \
            for (int i = 0; i < 2; ++i)                                      \
                _Pragma("unroll")                                            \
                for (int j = 0; j < 2; ++j)                                  \
                    acc[i][j] = __builtin_amdgcn_mfma_f32_16x16x32_bf16(     \
                        Ah[i][kt], buf[j * NKT + kt], acc[i][j], 0, 0, 0);   \
        const bool diagTile = (colBase == rowBase);                          \
        float colp[2] = {0.f, 0.f};                                          \
        _Pragma("unroll")                                                    \
        for (int i = 0; i < 2; ++i) {                                        \
            _Pragma("unroll")                                                \
            for (int j = 0; j < 2; ++j) {                                    \
                _Pragma("unroll")                                            \
                for (int reg = 0; reg < 4; ++reg) {                          \
                    float inner = acc[i][j][reg];                            \
                    float x = fmaxf(-inner, 1.000001f);                      \
                    float s = fast_sqrt(__builtin_fmaf(x, x, -1.0f));        \
                    float l2u = fast_log2(x + s);                            \
                    float e = fast_exp2(-14.285714285714286f * l2u);         \
                    rowp[i][reg] += e;                                       \
                    colp[j]      += e;                                       \
                    if (i == j && diagTile && (quad * 4 + reg) == l16) {     \
                        int R = rowBase + i * 16 + quad * 4 + reg;           \
                        diag[R] = -9.902102579427789f * l2u;                 \
                    }                                                        \
                }                                                            \
            }                                                                \
        }                                                                    \
        _Pragma("unroll")                                                    \
        for (int j = 0; j < 2; ++j) {                                        \
            float v = colp[j];                                               \
            v += __shfl_xor(v, 16);                                          \
            v += __shfl_xor(v, 32);                                          \
            if (quad == 0)                                                   \
                atomicAdd(&colRep[colBase + j * 16 + l16], v);               \
        }                                                                    \
    }

__global__ __launch_bounds__(256, 3) void gemm_epilogue_kernel(
    const unsigned short* __restrict__ A, const unsigned short* __restrict__ B,
    float* __restrict__ row_sum, float* __restrict__ col_part,
    float* __restrict__ diag)
{
    const int t    = threadIdx.x;
    const int lane = t & 63;
    const int wave = t >> 6;
    const int quad = lane >> 4;
    const int l16  = lane & 15;

    const int strip = blockIdx.x & 63;
    const int chunk = blockIdx.x >> 6;
    const int rowBase  = strip * 128 + wave * 32;   // wave's first row
    const int colChunk = chunk * 512;               // block's first col

    const unsigned short* Abase = A + (rowBase + l16) * K_PAD + quad * 8;
    float* colRep = col_part + (strip & 3) * BDIM;  // contention / 4

    // ---- hoist the entire A operand for this wave: 2 row-frags x 5 k-tiles
    bf16x8 Ah[2][NKT];
    #pragma unroll
    for (int i = 0; i < 2; ++i)
        #pragma unroll
        for (int kt = 0; kt < NKT; ++kt)
            Ah[i][kt] = *(const bf16x8*)(Abase + i * 16 * K_PAD + kt * BK);

    float rowp[2][4] = {};   // persistent across all col-tiles

    // ---- software pipeline: named double buffers, 2 tiles per iteration ----
    bf16x8 bufA[2 * NKT], bufB[2 * NKT];
    LOADB(bufA, colChunk);                       // prologue: tile 0

    #pragma unroll 1
    for (int ct2 = 0; ct2 < CTILES / 2; ++ct2) {
        const int c0 = colChunk + (ct2 * 2) * 32;
        // phase 0: prefetch tile (2*ct2+1) into bufB, compute tile (2*ct2)
        LOADB(bufB, c0 + 32);
        COMPUTE(bufA, c0);
        // phase 1: prefetch tile (2*ct2+2) into bufA, compute tile (2*ct2+1)
        if (ct2 < CTILES / 2 - 1)
            LOADB(bufA, c0 + 64);
        COMPUTE(bufB, c0 + 32);
    }

    // row sums: accumulated over all 16 col-tiles; reduce across the 16
    // lanes of each quad (they hold the cols), one atomic per row
    #pragma unroll
    for (int i = 0; i < 2; ++i) {
        #pragma unroll
        for (int reg = 0; reg < 4; ++reg) {
            float v = rowp[i][reg];
            v += __shfl_xor(v, 1);
            v += __shfl_xor(v, 2);
            v += __shfl_xor(v, 4);
            v += __shfl_xor(v, 8);
            if (l16 == 0)
                atomicAdd(&row_sum[rowBase + i * 16 + quad * 4 + reg], v);
        }
    }
}

// ---------------------------------------------------------------------------
// Kernel 3: loss = mean_b( 0.5*(ln rs[b] + ln cs[b]) - diag[b] ),
// cs[b] = sum of 4 replicas.
// ---------------------------------------------------------------------------
__global__ __launch_bounds__(1024) void finalize_kernel(
    const float* __restrict__ rs, const float* __restrict__ cp,
    const float* __restrict__ dg, float* __restrict__ out)
{
    __shared__ float part[16];
    int t = threadIdx.x;
    float a = 0.f;
    const float LN2_HALF = 0.34657359027997264f;  // 0.5 * ln2
    for (int b = t; b < BDIM; b += 1024) {
        float cs = cp[b] + cp[b + BDIM] + cp[b + 2 * BDIM] + cp[b + 3 * BDIM];
        a += LN2_HALF * (fast_log2(rs[b]) + fast_log2(cs)) - dg[b];
    }
    #pragma unroll
    for (int m = 1; m < 64; m <<= 1) a += __shfl_xor(a, m);
    if ((t & 63) == 0) part[t >> 6] = a;
    __syncthreads();
    if (t < 16) {
        float v = part[t];
        #pragma unroll
        for (int m = 1; m < 16; m <<= 1) v += __shfl_xor(v, m);
        if (t == 0) out[0] = v * (1.0f / (float)BDIM);
    }
}

// ---------------------------------------------------------------------------
extern "C" void kernel_launch(void* const* d_in, const int* in_sizes, int n_in,
                              void* d_out, int out_size, void* d_ws, size_t ws_size,
                              hipStream_t stream)
{
    const float* z1 = (const float*)d_in[0];
    const float* z2 = (const float*)d_in[1];
    float* out = (float*)d_out;

    char* ws = (char*)d_ws;
    unsigned short* A  = (unsigned short*)(ws + OFF_A);
    unsigned short* B  = (unsigned short*)(ws + OFF_B);
    float* row_sum     = (float*)(ws + OFF_RS);
    float* col_part    = (float*)(ws + OFF_CP);
    float* diag        = (float*)(ws + OFF_DG);

    convert_kernel<<<(BDIM * K_PAD + 255) / 256, 256, 0, stream>>>(
        z1, z2, A, B, row_sum /* rs + 4 col replicas contiguous */);

    gemm_epilogue_kernel<<<1024, 256, 0, stream>>>(
        A, B, row_sum, col_part, diag);

    finalize_kernel<<<1, 1024, 0, stream>>>(row_sum, col_part, diag, out);
}

// Round 3
// 120.767 us; speedup vs baseline: 1.0349x; 1.0096x over previous
//
#include <hip/hip_runtime.h>
#include <math.h>

// ---------------------------------------------------------------------------
// HyperbolicInfoNCE on MI355X — Round 9: sched_barrier-pinned prefetch.
//
// R8 post-mortem: VGPR_Count=84 proves the compiler merged/sank the named
// double buffer (Ah 40 + 2x40 bufs can't fit in 84). Source structure alone
// does NOT pin issue order; hipcc sinks loads to first use (3rd round in a
// row). Meanwhile VALUBusy*dur = 25.4us == hand-counted epilogue issue cost
// (6 VALU x 2cyc + 3 trans x 16cyc per 64-elem batch = 60cyc; 67.1M elems /
// 64 / 1024 SIMDs * 60 = 25.6us). The other ~38us is un-hidden load latency.
//
// R9: __builtin_amdgcn_sched_barrier(0) after each LOADB — a compile-time
// fence the scheduler cannot cross — forces tile ct+1's 10 B-loads to issue
// before tile ct's MFMA+epilogue (~1000cyc >> L2 latency). launch_bounds
// (256,2) gives the ~165-reg working set room (no spill risk; a pipelined
// wave's epilogue alone keeps the trans pipe ~80% fed, so 2 waves/SIMD
// suffice). Verification signal: VGPR_Count must jump to ~160-200.
// ---------------------------------------------------------------------------

#define BDIM   8192
#define K_IN   129
#define K_PAD  160      // 5 * 32
#define BK     32
#define NKT    (K_PAD / BK)   // 5
#define CTILES 16             // 32-col tiles per block (128 rows x 512 cols)

typedef __bf16  bf16x8 __attribute__((ext_vector_type(8)));
typedef float   f32x4  __attribute__((ext_vector_type(4)));

// ws layout (bytes)
#define OFF_A    0u
#define OFF_B    (BDIM * K_PAD * 2u)                  // 2,621,440
#define OFF_RS   (2u * BDIM * K_PAD * 2u)             // 5,242,880
#define OFF_CP   (OFF_RS + BDIM * 4u)                 // 4 replicas of col sums
#define OFF_DG   (OFF_CP + 4u * BDIM * 4u)

// ---- hardware transcendentals (v_sqrt_f32 / v_log_f32 / v_exp_f32) ----
__device__ __forceinline__ float fast_sqrt(float x) {
#if __has_builtin(__builtin_amdgcn_sqrtf)
    return __builtin_amdgcn_sqrtf(x);
#else
    return sqrtf(x);
#endif
}
__device__ __forceinline__ float fast_log2(float x) {
#if __has_builtin(__builtin_amdgcn_logf)
    return __builtin_amdgcn_logf(x);       // log base 2
#else
    return __log2f(x);
#endif
}
__device__ __forceinline__ float fast_exp2(float x) {
#if __has_builtin(__builtin_amdgcn_exp2f)
    return __builtin_amdgcn_exp2f(x);      // 2^x
#else
    extern "C" __device__ float __ocml_native_exp2_f32(float);
    return __ocml_native_exp2_f32(x);
#endif
}

__device__ __forceinline__ unsigned short f2bf_rne(float f) {
    unsigned int u = __float_as_uint(f);
    u += 0x7FFFu + ((u >> 16) & 1u);   // round-to-nearest-even
    return (unsigned short)(u >> 16);
}

// ---------------------------------------------------------------------------
// Kernel 1: fp32 -> bf16, K zero-padded 129->160, Lorentz metric folded into
// A (negate column 0 of z1). Also zeroes row_sum + 4 col_sum replicas.
// ---------------------------------------------------------------------------
__global__ __launch_bounds__(256) void convert_kernel(
    const float* __restrict__ z1, const float* __restrict__ z2,
    unsigned short* __restrict__ A, unsigned short* __restrict__ B,
    float* __restrict__ rs_cp)
{
    int idx = blockIdx.x * 256 + threadIdx.x;
    if (idx < 5 * BDIM) rs_cp[idx] = 0.f;
    if (idx >= BDIM * K_PAD) return;
    int r = idx / K_PAD;
    int c = idx - r * K_PAD;
    float va = 0.f, vb = 0.f;
    if (c < K_IN) {
        va = z1[r * K_IN + c];
        vb = z2[r * K_IN + c];
        if (c == 0) va = -va;          // Lorentz metric on first coordinate
    }
    A[idx] = f2bf_rne(va);
    B[idx] = f2bf_rne(vb);
}

// ---------------------------------------------------------------------------
// Kernel 2: strip-GEMM with fused acosh/exp epilogue, software-pipelined
// with compiler-proof fences.
//   grid = 1024: bid = chunk*64 + strip  (consecutive blocks share B-chunk)
//   block: rows [strip*128, +128) x cols [chunk*512, +512)
//   wave w (0..3): rows [strip*128 + w*32, +32), 16 col-tiles of 32
//   fragment layouts (guide-verified, m89/m91):
//     A/B operand: elem [m=lane&15][k=(lane>>4)*8 + j]
//     C/D:         elem [row=(lane>>4)*4 + reg][col=lane&15]
// ---------------------------------------------------------------------------

// Load the 10 B-fragments (2 col-frags x 5 k-tiles) of one 32-col tile.
// Fully unrolled -> all buffer indices compile-time (rule #20).
#define LOADB(buf, cb)                                                       \
    {                                                                        \
        const unsigned short* _Bb = B + ((cb) + l16) * K_PAD + quad * 8;     \
        _Pragma("unroll")                                                    \
        for (int _j = 0; _j < 2; ++_j)                                       \
            _Pragma("unroll")                                                \
            for (int _kt = 0; _kt < NKT; ++_kt)                              \
                buf[_j * NKT + _kt] =                                        \
                    *(const bf16x8*)(_Bb + _j * 16 * K_PAD + _kt * BK);      \
    }

// Compile-time fence: nothing may be scheduled across this point. Pins the
// preceding LOADB's issue before the following COMPUTE (the compiler has
// sunk reg-prefetch loads to first-use in R7/R8 — VGPR_Count proved it).
#define FENCE() __builtin_amdgcn_sched_barrier(0)

// MFMA + fused epilogue for one 32x32 tile using buffer `buf`.
#define COMPUTE(buf, cb)                                                     \
    {                                                                        \
        const int colBase = (cb);                                            \
        f32x4 acc[2][2] = {};                                                \
        _Pragma("unroll")                                                    \
        for (int kt = 0; kt < NKT; ++kt)                                     \
            _Pragma("unroll")                                                \
            for (int i = 0; i < 2; ++i)                                      \
                _Pragma("unroll")                                            \
                for (int j = 0; j < 2; ++j)                                  \
                    acc[i][j] = __builtin_amdgcn_mfma_f32_16x16x32_bf16(     \
                        Ah[i][kt], buf[j * NKT + kt], acc[i][j], 0, 0, 0);   \
        const bool diagTile = (colBase == rowBase);                          \
        float colp[2] = {0.f, 0.f};                                          \
        _Pragma("unroll")                                                    \
        for (int i = 0; i < 2; ++i) {                                        \
            _Pragma("unroll")                                                \
            for (int j = 0; j < 2; ++j) {                                    \
                _Pragma("unroll")                                            \
                for (int reg = 0; reg < 4; ++reg) {                          \
                    float inner = acc[i][j][reg];                            \
                    float x = fmaxf(-inner, 1.000001f);                      \
                    float s = fast_sqrt(__builtin_fmaf(x, x, -1.0f));        \
                    float l2u = fast_log2(x + s);                            \
                    float e = fast_exp2(-14.285714285714286f * l2u);         \
                    rowp[i][reg] += e;                                       \
                    colp[j]      += e;                                       \
                    if (i == j && diagTile && (quad * 4 + reg) == l16) {     \
                        int R = rowBase + i * 16 + quad * 4 + reg;           \
                        diag[R] = -9.902102579427789f * l2u;                 \
                    }                                                        \
                }                                                            \
            }                                                                \
        }                                                                    \
        _Pragma("unroll")                                                    \
        for (int j = 0; j < 2; ++j) {                                        \
            float v = colp[j];                                               \
            v += __shfl_xor(v, 16);                                          \
            v += __shfl_xor(v, 32);                                          \
            if (quad == 0)                                                   \
                atomicAdd(&colRep[colBase + j * 16 + l16], v);               \
        }                                                                    \
    }

__global__ __launch_bounds__(256, 2) void gemm_epilogue_kernel(
    const unsigned short* __restrict__ A, const unsigned short* __restrict__ B,
    float* __restrict__ row_sum, float* __restrict__ col_part,
    float* __restrict__ diag)
{
    const int t    = threadIdx.x;
    const int lane = t & 63;
    const int wave = t >> 6;
    const int quad = lane >> 4;
    const int l16  = lane & 15;

    const int strip = blockIdx.x & 63;
    const int chunk = blockIdx.x >> 6;
    const int rowBase  = strip * 128 + wave * 32;   // wave's first row
    const int colChunk = chunk * 512;               // block's first col

    const unsigned short* Abase = A + (rowBase + l16) * K_PAD + quad * 8;
    float* colRep = col_part + (strip & 3) * BDIM;  // contention / 4

    // ---- hoist the entire A operand for this wave: 2 row-frags x 5 k-tiles
    bf16x8 Ah[2][NKT];
    #pragma unroll
    for (int i = 0; i < 2; ++i)
        #pragma unroll
        for (int kt = 0; kt < NKT; ++kt)
            Ah[i][kt] = *(const bf16x8*)(Abase + i * 16 * K_PAD + kt * BK);

    float rowp[2][4] = {};   // persistent across all col-tiles

    // ---- software pipeline: named double buffers + sched_barrier fences,
    //      2 tiles per iteration ----
    bf16x8 bufA[2 * NKT], bufB[2 * NKT];
    LOADB(bufA, colChunk);                       // prologue: tile 0
    FENCE();

    #pragma unroll 1
    for (int ct2 = 0; ct2 < CTILES / 2; ++ct2) {
        const int c0 = colChunk + (ct2 * 2) * 32;
        // phase 0: prefetch tile (2*ct2+1) into bufB, compute tile (2*ct2)
        LOADB(bufB, c0 + 32);
        FENCE();
        COMPUTE(bufA, c0);
        // phase 1: prefetch tile (2*ct2+2) into bufA, compute tile (2*ct2+1)
        if (ct2 < CTILES / 2 - 1) {
            LOADB(bufA, c0 + 64);
        }
        FENCE();
        COMPUTE(bufB, c0 + 32);
    }

    // row sums: accumulated over all 16 col-tiles; reduce across the 16
    // lanes of each quad (they hold the cols), one atomic per row
    #pragma unroll
    for (int i = 0; i < 2; ++i) {
        #pragma unroll
        for (int reg = 0; reg < 4; ++reg) {
            float v = rowp[i][reg];
            v += __shfl_xor(v, 1);
            v += __shfl_xor(v, 2);
            v += __shfl_xor(v, 4);
            v += __shfl_xor(v, 8);
            if (l16 == 0)
                atomicAdd(&row_sum[rowBase + i * 16 + quad * 4 + reg], v);
        }
    }
}

// ---------------------------------------------------------------------------
// Kernel 3: loss = mean_b( 0.5*(ln rs[b] + ln cs[b]) - diag[b] ),
// cs[b] = sum of 4 replicas.
// ---------------------------------------------------------------------------
__global__ __launch_bounds__(1024) void finalize_kernel(
    const float* __restrict__ rs, const float* __restrict__ cp,
    const float* __restrict__ dg, float* __restrict__ out)
{
    __shared__ float part[16];
    int t = threadIdx.x;
    float a = 0.f;
    const float LN2_HALF = 0.34657359027997264f;  // 0.5 * ln2
    for (int b = t; b < BDIM; b += 1024) {
        float cs = cp[b] + cp[b + BDIM] + cp[b + 2 * BDIM] + cp[b + 3 * BDIM];
        a += LN2_HALF * (fast_log2(rs[b]) + fast_log2(cs)) - dg[b];
    }
    #pragma unroll
    for (int m = 1; m < 64; m <<= 1) a += __shfl_xor(a, m);
    if ((t & 63) == 0) part[t >> 6] = a;
    __syncthreads();
    if (t < 16) {
        float v = part[t];
        #pragma unroll
        for (int m = 1; m < 16; m <<= 1) v += __shfl_xor(v, m);
        if (t == 0) out[0] = v * (1.0f / (float)BDIM);
    }
}

// ---------------------------------------------------------------------------
extern "C" void kernel_launch(void* const* d_in, const int* in_sizes, int n_in,
                              void* d_out, int out_size, void* d_ws, size_t ws_size,
                              hipStream_t stream)
{
    const float* z1 = (const float*)d_in[0];
    const float* z2 = (const float*)d_in[1];
    float* out = (float*)d_out;

    char* ws = (char*)d_ws;
    unsigned short* A  = (unsigned short*)(ws + OFF_A);
    unsigned short* B  = (unsigned short*)(ws + OFF_B);
    float* row_sum     = (float*)(ws + OFF_RS);
    float* col_part    = (float*)(ws + OFF_CP);
    float* diag        = (float*)(ws + OFF_DG);

    convert_kernel<<<(BDIM * K_PAD + 255) / 256, 256, 0, stream>>>(
        z1, z2, A, B, row_sum /* rs + 4 col replicas contiguous */);

    gemm_epilogue_kernel<<<1024, 256, 0, stream>>>(
        A, B, row_sum, col_part, diag);

    finalize_kernel<<<1, 1024, 0, stream>>>(row_sum, col_part, diag, out);
}

// Round 4
// 108.837 us; speedup vs baseline: 1.1484x; 1.1096x over previous
//
#include <hip/hip_runtime.h>
#include <math.h>

// ---------------------------------------------------------------------------
// HyperbolicInfoNCE on MI355X — Round 10: LDS double-buffered B staging via
// global_load_lds (the compiler-proof async path).
//
// R7-R9 post-mortem: three attempts at register-level B prefetch (named
// double buffers, sched_barrier(0) fences) all collapsed to VGPR_Count=84 —
// plain loads have no side effects, so IR-level sinking moves them to first
// use regardless of source structure or scheduler fences. dur stuck at
// ~61.5us with VALUBusy 40% (= the 25.6us transcendental-issue floor over a
// stalled 61.5us wall).
//
// R10: B-operand goes through LDS, double-buffered. global_load_lds IS
// side-effecting (writes LDS) -> hipcc cannot sink it past potentially
// aliasing ds_reads / barriers; vmcnt tracks it in HW. Per 64-col tile:
//   STAGE(next tile -> Bs[n^1])   // 5 async 1KB issues per wave, 20KB total
//   COMPUTE(cur tile from Bs[n])  // ds_read_b128 + 40 MFMA + ~1900cy epilogue
//   __syncthreads()               // vmcnt(0) drain is free (loads long done)
// B-tile = 32..64 consecutive rows of the pre-transposed B array = a
// CONTIGUOUS 20KB chunk -> linear lane mapping for global_load_lds (m104
// constraint satisfied). ds_read_b128 fragment reads: 8 lanes on each of 8
// disjoint 4-bank groups = dense-optimal for b128 (no padding needed).
// LDS 40KB, Ah in regs (40 VGPR), launch_bounds(256,3).
// ---------------------------------------------------------------------------

#define BDIM   8192
#define K_IN   129
#define K_PAD  160      // 5 * 32
#define BK     32
#define NKT    (K_PAD / BK)   // 5
#define CTILES 8              // 64-col tiles per block (128 rows x 512 cols)

typedef __bf16  bf16x8 __attribute__((ext_vector_type(8)));
typedef float   f32x4  __attribute__((ext_vector_type(4)));

// ws layout (bytes)
#define OFF_A    0u
#define OFF_B    (BDIM * K_PAD * 2u)                  // 2,621,440
#define OFF_RS   (2u * BDIM * K_PAD * 2u)             // 5,242,880
#define OFF_CP   (OFF_RS + BDIM * 4u)                 // 4 replicas of col sums
#define OFF_DG   (OFF_CP + 4u * BDIM * 4u)

// ---- hardware transcendentals (v_sqrt_f32 / v_log_f32 / v_exp_f32) ----
__device__ __forceinline__ float fast_sqrt(float x) {
#if __has_builtin(__builtin_amdgcn_sqrtf)
    return __builtin_amdgcn_sqrtf(x);
#else
    return sqrtf(x);
#endif
}
__device__ __forceinline__ float fast_log2(float x) {
#if __has_builtin(__builtin_amdgcn_logf)
    return __builtin_amdgcn_logf(x);       // log base 2
#else
    return __log2f(x);
#endif
}
__device__ __forceinline__ float fast_exp2(float x) {
#if __has_builtin(__builtin_amdgcn_exp2f)
    return __builtin_amdgcn_exp2f(x);      // 2^x
#else
    extern "C" __device__ float __ocml_native_exp2_f32(float);
    return __ocml_native_exp2_f32(x);
#endif
}

__device__ __forceinline__ unsigned short f2bf_rne(float f) {
    unsigned int u = __float_as_uint(f);
    u += 0x7FFFu + ((u >> 16) & 1u);   // round-to-nearest-even
    return (unsigned short)(u >> 16);
}

// ---------------------------------------------------------------------------
// Kernel 1: fp32 -> bf16, K zero-padded 129->160, Lorentz metric folded into
// A (negate column 0 of z1). Also zeroes row_sum + 4 col_sum replicas.
// ---------------------------------------------------------------------------
__global__ __launch_bounds__(256) void convert_kernel(
    const float* __restrict__ z1, const float* __restrict__ z2,
    unsigned short* __restrict__ A, unsigned short* __restrict__ B,
    float* __restrict__ rs_cp)
{
    int idx = blockIdx.x * 256 + threadIdx.x;
    if (idx < 5 * BDIM) rs_cp[idx] = 0.f;
    if (idx >= BDIM * K_PAD) return;
    int r = idx / K_PAD;
    int c = idx - r * K_PAD;
    float va = 0.f, vb = 0.f;
    if (c < K_IN) {
        va = z1[r * K_IN + c];
        vb = z2[r * K_IN + c];
        if (c == 0) va = -va;          // Lorentz metric on first coordinate
    }
    A[idx] = f2bf_rne(va);
    B[idx] = f2bf_rne(vb);
}

// ---------------------------------------------------------------------------
// Kernel 2: strip-GEMM with fused acosh/exp epilogue; B staged through a
// double-buffered LDS pipeline (global_load_lds, T3 minimum recipe).
//   grid = 1024: bid = chunk*64 + strip  (consecutive blocks share B-chunk)
//   block: rows [strip*128, +128) x cols [chunk*512, +512)
//   wave w (0..3): rows [strip*128 + w*32, +32), 8 col-tiles of 64
//   fragment layouts (guide-verified, m89/m91):
//     A/B operand: elem [m=lane&15][k=(lane>>4)*8 + j]
//     C/D:         elem [row=(lane>>4)*4 + reg][col=lane&15]
// ---------------------------------------------------------------------------

// Stage one 64-col B-tile (20KB contiguous global chunk) into Bs[bufidx].
// Each wave issues 5 async 1KB copies (64 lanes x 16B); HW places each
// lane's 16B at lds_base + lane*16 (wave-uniform base requirement, m104).
#define STAGE(bufidx, cb)                                                     \
    {                                                                         \
        const char* _gp = (const char*)(B + (size_t)(cb) * K_PAD)             \
                          + wave * 5120 + lane * 16;                          \
        unsigned short* _lp = &Bs[bufidx][wave * 2560];                       \
        _Pragma("unroll")                                                     \
        for (int _i = 0; _i < 5; ++_i)                                        \
            __builtin_amdgcn_global_load_lds(                                 \
                (const __attribute__((address_space(1))) void*)               \
                    (_gp + _i * 1024),                                        \
                (__attribute__((address_space(3))) void*)(_lp + _i * 512),    \
                16, 0, 0);                                                    \
    }

// MFMA + fused epilogue for one 32x64 wave-tile read from Bs[bufidx].
#define COMPUTE(bufidx, cb)                                                   \
    {                                                                         \
        const int colBase = (cb);                                             \
        const unsigned short* _Bt = &Bs[bufidx][0];                           \
        f32x4 acc[2][4] = {};                                                 \
        _Pragma("unroll")                                                     \
        for (int kt = 0; kt < NKT; ++kt) {                                    \
            bf16x8 bfr[4];                                                    \
            _Pragma("unroll")                                                 \
            for (int j = 0; j < 4; ++j)                                       \
                bfr[j] = *(const bf16x8*)                                     \
                    &_Bt[(l16 + j * 16) * K_PAD + quad * 8 + kt * BK];        \
            _Pragma("unroll")                                                 \
            for (int i = 0; i < 2; ++i)                                       \
                _Pragma("unroll")                                             \
                for (int j = 0; j < 4; ++j)                                   \
                    acc[i][j] = __builtin_amdgcn_mfma_f32_16x16x32_bf16(      \
                        Ah[i][kt], bfr[j], acc[i][j], 0, 0, 0);               \
        }                                                                     \
        const bool diagTile = (colBase == (rowBase & ~63));                   \
        const int  dj       = (rowBase >> 4) & 2;                             \
        float colp[4] = {0.f, 0.f, 0.f, 0.f};                                 \
        _Pragma("unroll")                                                     \
        for (int i = 0; i < 2; ++i) {                                         \
            _Pragma("unroll")                                                 \
            for (int j = 0; j < 4; ++j) {                                     \
                _Pragma("unroll")                                             \
                for (int reg = 0; reg < 4; ++reg) {                           \
                    float inner = acc[i][j][reg];                             \
                    float x = fmaxf(-inner, 1.000001f);                       \
                    float s = fast_sqrt(__builtin_fmaf(x, x, -1.0f));         \
                    float l2u = fast_log2(x + s);                             \
                    float e = fast_exp2(-14.285714285714286f * l2u);          \
                    rowp[i][reg] += e;                                        \
                    colp[j]      += e;                                        \
                    if (diagTile && (j - i) == dj && (quad * 4 + reg) == l16){\
                        int R = rowBase + i * 16 + quad * 4 + reg;            \
                        diag[R] = -9.902102579427789f * l2u;                  \
                    }                                                         \
                }                                                             \
            }                                                                 \
        }                                                                     \
        _Pragma("unroll")                                                     \
        for (int j = 0; j < 4; ++j) {                                         \
            float v = colp[j];                                                \
            v += __shfl_xor(v, 16);                                           \
            v += __shfl_xor(v, 32);                                           \
            if (quad == 0)                                                    \
                atomicAdd(&colRep[colBase + j * 16 + l16], v);                \
        }                                                                     \
    }

__global__ __launch_bounds__(256, 3) void gemm_epilogue_kernel(
    const unsigned short* __restrict__ A, const unsigned short* __restrict__ B,
    float* __restrict__ row_sum, float* __restrict__ col_part,
    float* __restrict__ diag)
{
    const int t    = threadIdx.x;
    const int lane = t & 63;
    const int wave = t >> 6;
    const int quad = lane >> 4;
    const int l16  = lane & 15;

    const int strip = blockIdx.x & 63;
    const int chunk = blockIdx.x >> 6;
    const int rowBase  = strip * 128 + wave * 32;   // wave's first row
    const int colChunk = chunk * 512;               // block's first col

    const unsigned short* Abase = A + (rowBase + l16) * K_PAD + quad * 8;
    float* colRep = col_part + (strip & 3) * BDIM;  // contention / 4

    // B-tile double buffer: [64 cols][160 k] linear (byte-for-byte copy of
    // the contiguous global chunk).
    __shared__ __align__(16) unsigned short Bs[2][64 * K_PAD];

    // ---- hoist the entire A operand for this wave: 2 row-frags x 5 k-tiles
    bf16x8 Ah[2][NKT];
    #pragma unroll
    for (int i = 0; i < 2; ++i)
        #pragma unroll
        for (int kt = 0; kt < NKT; ++kt)
            Ah[i][kt] = *(const bf16x8*)(Abase + i * 16 * K_PAD + kt * BK);

    float rowp[2][4] = {};   // persistent across all col-tiles

    // ---- 2-phase pipeline: stage next tile, compute current, one barrier
    STAGE(0, colChunk);                  // prologue: tile 0 -> Bs[0]
    __syncthreads();

    #pragma unroll 1
    for (int ct = 0; ct < CTILES; ++ct) {
        if (ct + 1 < CTILES)
            STAGE((ct + 1) & 1, colChunk + (ct + 1) * 64);
        COMPUTE(ct & 1, colChunk + ct * 64);
        __syncthreads();                 // vmcnt(0)+barrier: loads long done
    }

    // row sums: accumulated over all 8 col-tiles; reduce across the 16
    // lanes of each quad (they hold the cols), one atomic per row
    #pragma unroll
    for (int i = 0; i < 2; ++i) {
        #pragma unroll
        for (int reg = 0; reg < 4; ++reg) {
            float v = rowp[i][reg];
            v += __shfl_xor(v, 1);
            v += __shfl_xor(v, 2);
            v += __shfl_xor(v, 4);
            v += __shfl_xor(v, 8);
            if (l16 == 0)
                atomicAdd(&row_sum[rowBase + i * 16 + quad * 4 + reg], v);
        }
    }
}

// ---------------------------------------------------------------------------
// Kernel 3: loss = mean_b( 0.5*(ln rs[b] + ln cs[b]) - diag[b] ),
// cs[b] = sum of 4 replicas.
// ---------------------------------------------------------------------------
__global__ __launch_bounds__(1024) void finalize_kernel(
    const float* __restrict__ rs, const float* __restrict__ cp,
    const float* __restrict__ dg, float* __restrict__ out)
{
    __shared__ float part[16];
    int t = threadIdx.x;
    float a = 0.f;
    const float LN2_HALF = 0.34657359027997264f;  // 0.5 * ln2
    for (int b = t; b < BDIM; b += 1024) {
        float cs = cp[b] + cp[b + BDIM] + cp[b + 2 * BDIM] + cp[b + 3 * BDIM];
        a += LN2_HALF * (fast_log2(rs[b]) + fast_log2(cs)) - dg[b];
    }
    #pragma unroll
    for (int m = 1; m < 64; m <<= 1) a += __shfl_xor(a, m);
    if ((t & 63) == 0) part[t >> 6] = a;
    __syncthreads();
    if (t < 16) {
        float v = part[t];
        #pragma unroll
        for (int m = 1; m < 16; m <<= 1) v += __shfl_xor(v, m);
        if (t == 0) out[0] = v * (1.0f / (float)BDIM);
    }
}

// ---------------------------------------------------------------------------
extern "C" void kernel_launch(void* const* d_in, const int* in_sizes, int n_in,
                              void* d_out, int out_size, void* d_ws, size_t ws_size,
                              hipStream_t stream)
{
    const float* z1 = (const float*)d_in[0];
    const float* z2 = (const float*)d_in[1];
    float* out = (float*)d_out;

    char* ws = (char*)d_ws;
    unsigned short* A  = (unsigned short*)(ws + OFF_A);
    unsigned short* B  = (unsigned short*)(ws + OFF_B);
    float* row_sum     = (float*)(ws + OFF_RS);
    float* col_part    = (float*)(ws + OFF_CP);
    float* diag        = (float*)(ws + OFF_DG);

    convert_kernel<<<(BDIM * K_PAD + 255) / 256, 256, 0, stream>>>(
        z1, z2, A, B, row_sum /* rs + 4 col replicas contiguous */);

    gemm_epilogue_kernel<<<1024, 256, 0, stream>>>(
        A, B, row_sum, col_part, diag);

    finalize_kernel<<<1, 1024, 0, stream>>>(row_sum, col_part, diag, out);
}